// Round 1
// baseline (270.539 us; speedup 1.0000x reference)
//
#include <hip/hip_runtime.h>
#include <hip/hip_bf16.h>
#include <stdint.h>

#define Bn 4
#define Cn 64
#define Fn 50000
#define Kn 16
#define NTOT (Bn*Fn)
#define EPS 1e-5f

typedef unsigned short u16;
typedef unsigned int u32;

__device__ __forceinline__ u16 f2bf(float x) {
  __hip_bfloat16 h = __float2bfloat16(x);
  return *reinterpret_cast<u16*>(&h);
}

// K1: Gt[b][f][o] = sum_c W[o][c] * fea[b][c][f], bf16 output.
// grid (391, 4) = (ceil(F/128), B), 256 threads. 4o x 8f register tile/thread.
__global__ __launch_bounds__(256) void k1_wgemm(
    const float* __restrict__ fea, const float* __restrict__ W,
    u16* __restrict__ Gt) {
  const int b = blockIdx.y;
  const int f0 = blockIdx.x * 128;
  __shared__ float a_s[64][132];   // [c][f] tile, stride keeps 16B align
  __shared__ float w_s[64][68];    // [c][o] (transposed W)
  const int t = threadIdx.x;
  {
    const float4* W4 = (const float4*)W;  // 1024 float4 total
    #pragma unroll
    for (int jj = 0; jj < 4; ++jj) {
      int l = jj * 256 + t;
      float4 v = W4[l];
      int o = l >> 4;
      int c = (l & 15) << 2;
      w_s[c][o] = v.x; w_s[c+1][o] = v.y; w_s[c+2][o] = v.z; w_s[c+3][o] = v.w;
    }
  }
  {
    const float* fb = fea + ((size_t)b * Cn) * Fn + f0;
    #pragma unroll
    for (int jj = 0; jj < 8; ++jj) {
      int l = jj * 256 + t;        // float4 index within 64x128 tile
      int c = l >> 5;
      int fi = (l & 31) << 2;
      float4 v = make_float4(0.f, 0.f, 0.f, 0.f);
      if (f0 + fi < Fn) v = *(const float4*)(fb + (size_t)c * Fn + fi);
      *(float4*)&a_s[c][fi] = v;
    }
  }
  __syncthreads();
  const int fgrp = t & 15, ogrp = t >> 4;
  float acc[4][8];
  #pragma unroll
  for (int i = 0; i < 4; i++)
    #pragma unroll
    for (int j = 0; j < 8; j++) acc[i][j] = 0.f;
  #pragma unroll 4
  for (int c = 0; c < 64; c++) {
    float4 w  = *(float4*)&w_s[c][ogrp << 2];
    float4 a0 = *(float4*)&a_s[c][fgrp << 3];
    float4 a1 = *(float4*)&a_s[c][(fgrp << 3) + 4];
    float wv[4] = {w.x, w.y, w.z, w.w};
    float av[8] = {a0.x, a0.y, a0.z, a0.w, a1.x, a1.y, a1.z, a1.w};
    #pragma unroll
    for (int i = 0; i < 4; i++)
      #pragma unroll
      for (int j = 0; j < 8; j++) acc[i][j] = fmaf(wv[i], av[j], acc[i][j]);
  }
  const int o0 = ogrp << 2;
  #pragma unroll
  for (int j = 0; j < 8; j++) {
    int f = f0 + (fgrp << 3) + j;
    if (f < Fn) {
      ushort4 u;
      u.x = f2bf(acc[0][j]); u.y = f2bf(acc[1][j]);
      u.z = f2bf(acc[2][j]); u.w = f2bf(acc[3][j]);
      *(ushort4*)(Gt + ((size_t)b * Fn + f) * 64 + o0) = u;
    }
  }
}

// K2: per (b, 64-face tile): y = sum_k Gt[b][ring[f][k]][:] + bias;
// write y to out [b][o][f] via LDS transpose; per-channel partial stats.
__global__ __launch_bounds__(256) void k2_gather(
    const u16* __restrict__ Gt, const int* __restrict__ ring,
    const float* __restrict__ bias, float* __restrict__ out,
    float* __restrict__ gsum, float* __restrict__ gsum2) {
  const int bid = blockIdx.x;
  const int b = bid & 3;           // batch<->XCD affinity (blocks round-robin XCDs)
  const int f0 = (bid >> 2) * 64;
  const int t = threadIdx.x;
  __shared__ int idx_s[64 * 17];   // pad 17: conflict-free reads
  __shared__ float y_s[64][65];    // [face][chan], stride 65: conflict-free both ways
  __shared__ float bias_s[64];
  __shared__ float rs[4][64];
  __shared__ float rs2[4][64];
  const int nvalid = min(64, Fn - f0);
  {
    const int* rp = ring + ((size_t)b * Fn + f0) * Kn;
    const int nl = nvalid * Kn;
    #pragma unroll
    for (int jj = 0; jj < 4; ++jj) {
      int l = jj * 256 + t;
      if (l < nl) idx_s[(l >> 4) * 17 + (l & 15)] = rp[l];
    }
  }
  if (t < 64) bias_s[t] = bias[t];
  __syncthreads();
  const int face = t >> 2;   // 4 threads per face
  const int seg = t & 3;     // 16 channels each (32B of the bf16 row)
  float acc[16];
  #pragma unroll
  for (int i = 0; i < 16; i++) acc[i] = 0.f;
  const bool valid = face < nvalid;
  if (valid) {
    const int* my = idx_s + face * 17;
    const u16* gb = Gt + (size_t)b * Fn * 64 + seg * 16;
    #pragma unroll
    for (int k = 0; k < Kn; k++) {
      int j = my[k];
      const uint4* g = (const uint4*)(gb + (size_t)j * 64);
      uint4 u0 = g[0];
      uint4 u1 = g[1];
      u32 uu[8] = {u0.x, u0.y, u0.z, u0.w, u1.x, u1.y, u1.z, u1.w};
      #pragma unroll
      for (int m = 0; m < 8; m++) {
        acc[2*m]   += __uint_as_float(uu[m] << 16);
        acc[2*m+1] += __uint_as_float(uu[m] & 0xffff0000u);
      }
    }
  }
  {
    const int c0 = seg * 16;
    #pragma unroll
    for (int i = 0; i < 16; i++) {
      y_s[face][c0 + i] = valid ? acc[i] + bias_s[c0 + i] : 0.f;
    }
  }
  __syncthreads();
  {  // coalesced store: lanes sweep faces, rows sweep channels
    const int f_l = t & 63;
    const int wrow = t >> 6;
    if (f_l < nvalid) {
      float* ob = out + ((size_t)b * Cn) * Fn + f0 + f_l;
      #pragma unroll
      for (int j = 0; j < 16; j++) {
        int o = wrow * 16 + j;
        ob[(size_t)o * Fn] = y_s[f_l][o];
      }
    }
  }
  {  // per-channel partial sums over this tile's 64 faces
    const int o = t & 63;
    const int part = t >> 6;
    float s = 0.f, s2 = 0.f;
    #pragma unroll
    for (int i = 0; i < 16; i++) {
      float v = y_s[part * 16 + i][o];
      s += v; s2 += v * v;
    }
    rs[part][o] = s; rs2[part][o] = s2;
  }
  __syncthreads();
  if (t < 64) {
    float s  = rs[0][t] + rs[1][t] + rs[2][t] + rs[3][t];
    float s2 = rs2[0][t] + rs2[1][t] + rs2[2][t] + rs2[3][t];
    atomicAdd(&gsum[t], s);
    atomicAdd(&gsum2[t], s2);
  }
}

__global__ void k3_stats(const float* __restrict__ gsum, const float* __restrict__ gsum2,
                         const float* __restrict__ gamma, const float* __restrict__ beta,
                         float* __restrict__ ab) {
  int o = threadIdx.x;
  if (o < 64) {
    float inv = 1.0f / (float)NTOT;
    float mean = gsum[o] * inv;
    float var = gsum2[o] * inv - mean * mean;  // biased, as torch BN normalize
    float r = rsqrtf(var + EPS);
    float a = gamma[o] * r;
    ab[o] = a;
    ab[64 + o] = beta[o] - mean * a;
  }
}

__global__ __launch_bounds__(256) void k4_norm(float* __restrict__ out,
                                               const float* __restrict__ ab) {
  int i = blockIdx.x * 256 + threadIdx.x;     // float4 index, exact cover
  int o = (i / (Fn / 4)) & 63;
  float a = ab[o], c = ab[64 + o];
  float4 v = ((float4*)out)[i];
  v.x = fmaxf(fmaf(v.x, a, c), 0.f);
  v.y = fmaxf(fmaf(v.y, a, c), 0.f);
  v.z = fmaxf(fmaf(v.z, a, c), 0.f);
  v.w = fmaxf(fmaf(v.w, a, c), 0.f);
  ((float4*)out)[i] = v;
}

extern "C" void kernel_launch(void* const* d_in, const int* in_sizes, int n_in,
                              void* d_out, int out_size, void* d_ws, size_t ws_size,
                              hipStream_t stream) {
  const float* fea   = (const float*)d_in[0];
  const int*   ring  = (const int*)d_in[1];
  const float* W     = (const float*)d_in[2];
  const float* bias  = (const float*)d_in[3];
  const float* gamma = (const float*)d_in[4];
  const float* beta  = (const float*)d_in[5];
  float* out = (float*)d_out;

  u16* Gt = (u16*)d_ws;
  const size_t statsOff = (size_t)Bn * Fn * 64 * 2;  // 25.6 MB
  float* gsum  = (float*)((char*)d_ws + statsOff);
  float* gsum2 = gsum + 64;
  float* ab    = gsum + 128;

  hipMemsetAsync(gsum, 0, 2 * 64 * sizeof(float), stream);
  k1_wgemm<<<dim3((Fn + 127) / 128, Bn), 256, 0, stream>>>(fea, W, Gt);
  k2_gather<<<dim3(((Fn + 63) / 64) * Bn), 256, 0, stream>>>(Gt, ring, bias, out, gsum, gsum2);
  k3_stats<<<1, 64, 0, stream>>>(gsum, gsum2, gamma, beta, ab);
  k4_norm<<<dim3((Bn * Cn * Fn / 4) / 256), 256, 0, stream>>>(out, ab);
}